// Round 14
// baseline (38.563 us; speedup 1.0000x reference)
//
#include <hip/hip_runtime.h>

namespace {

constexpr int Nn = 256;
constexpr int Bn = 64;
constexpr int SEG = 8;
constexpr int NSEG = Nn / SEG;   // 32

// Gaussian taps, sigma = 5*0.15+0.35 = 1.1
constexpr float KW0 = 0.07076638f;
constexpr float KW1 = 0.24446039f;
constexpr float KW2 = 0.36954646f;

constexpr float DEF_OFF   = 1.00784313725490196f;   // 1 + 2/255
constexpr float SCALE     = 0.01568627450980392f;   // 4/255
constexpr float INV_SCALE = 63.75f;                 // 255/4
constexpr float TWO255    = 0.00784313725490196f;   // 2/255 = seq step
constexpr float PW        = 0.0078125f;             // 2/256

__device__ __forceinline__ int reflN(int i) {
    if (i < 0) i = -i;
    if (i >= Nn) i = 2 * (Nn - 1) - i;
    return i;
}

__device__ __forceinline__ float seqf(int t) {
    return (float)(2 * t - (Nn - 1)) * (1.0f / (float)(Nn - 1));
}

// Bijective XCD swizzle: 2048 blocks, 8 XCDs, 256-block chunks
// -> all 32 segs of a batch (8 whole batches) share one XCD's L2.
__device__ __forceinline__ void segb(int lin, int& seg, int& b) {
    int wg = (lin & 7) * 256 + (lin >> 3);
    b = wg >> 5;
    seg = wg & (NSEG - 1);
}

// ---- kP: ch1 conv -> per-segment column partial sums (2MB) -----------------
__global__ __launch_bounds__(256, 8) void kP_kernel(const float* __restrict__ prim,
                                                    float* __restrict__ partial) {
    const int j = threadIdx.x;
    int seg, b;
    segb(blockIdx.x, seg, b);
    const int i0 = seg * SEG;
    const float* c1 = prim + ((size_t)b * 2 + 1) * Nn * Nn;

    float a[SEG + 5];
    #pragma unroll
    for (int t = 0; t < SEG + 5; ++t) a[t] = c1[reflN(i0 - 3 + t) * Nn + j];

    __shared__ float vb[(SEG + 1) * Nn];
    #pragma unroll
    for (int r = 0; r < SEG + 1; ++r)   // v-conv centers i0-1 .. i0+7
        vb[r * Nn + j] = KW0 * (a[r] + a[r + 4]) + KW1 * (a[r + 1] + a[r + 3]) + KW2 * a[r + 2];
    __syncthreads();

    const int jm2 = reflN(j - 2), jm1 = reflN(j - 1), jp1 = reflN(j + 1), jp2 = reflN(j + 2);
    auto hc = [&](const float* v) {
        return KW0 * (v[jm2] + v[jp2]) + KW1 * (v[jm1] + v[jp1]) + KW2 * v[j];
    };

    float hprev = hc(&vb[0]);
    float psum = 0.0f;
    #pragma unroll
    for (int r = 0; r < SEG; ++r) {
        float h = hc(&vb[(r + 1) * Nn]);
        float hm = (r == 0 && seg == 0) ? 0.0f : hprev;
        psum += fmaxf((h - hm + TWO255) * INV_SCALE, 0.0f);
        hprev = h;
    }
    partial[((size_t)b * NSEG + seg) * Nn + j] = psum;
}

// ---- kF: conv + scans + cumsum + channel-pipelined bilinear ----------------
// LDS: two 10-row buffers (21KB) -> HW allows 7 blocks/CU.
// bounds(256,4): VGPR cap 128 — the allocator must NOT be forced tighter
// (R8/R9/R11: tighter bounds or bigger arrays => ~100MB scratch spill traffic).
__global__ __launch_bounds__(256, 4) void kF_kernel(const float* __restrict__ prim,
                                                    const float* __restrict__ image,
                                                    const float* __restrict__ partial,
                                                    float* __restrict__ outp) {
    const int j = threadIdx.x;
    int seg, b;
    segb(blockIdx.x, seg, b);
    const int i0 = seg * SEG;
    const int lane = j & 63;
    const int wave = j >> 6;

    __shared__ float bufA[SEG + 2][Nn];   // 10KB
    __shared__ float bufB[SEG + 2][Nn];   // 10KB
    __shared__ float wsum[SEG][4];

    // async image-channel prefetch: 10 rows, one 16B DMA per lane per row
    auto issue_prefetch = [&](int c, float (*buf)[Nn]) {
        for (int r = wave; r < SEG + 2; r += 4) {
            int row = min(max(i0 - 1 + r, 0), Nn - 1);
            const float* src = image + ((size_t)(b * 3 + c) * Nn + row) * Nn + lane * 4;
#if defined(__has_builtin) && __has_builtin(__builtin_amdgcn_global_load_lds)
            __builtin_amdgcn_global_load_lds(
                (const __attribute__((address_space(1))) void*)(const void*)src,
                (__attribute__((address_space(3))) void*)(void*)&buf[r][0],
                16, 0, 0);
#else
            ((float4*)&buf[r][0])[lane] = ((const float4*)(src - lane * 4))[lane];
#endif
        }
    };

    // ---- 1) start c0 DMA immediately (overlaps both conv phases) ----
    issue_prefetch(0, bufA);

    const float* c0 = prim + (size_t)b * 2 * Nn * Nn;
    const float* c1 = c0 + (size_t)Nn * Nn;

    // ---- 2) exclusive carry over preceding segments (L2-resident) ----
    const float* pb = partial + (size_t)b * NSEG * Nn + j;
    float carry = 0.0f;
    #pragma unroll
    for (int k = 0; k < NSEG - 1; ++k) {
        float p = pb[(size_t)k * Nn];
        carry += (k < seg) ? p : 0.0f;
    }

    const int jm3 = reflN(j - 3), jm2 = reflN(j - 2), jm1 = reflN(j - 1),
              jp1 = reflN(j + 1), jp2 = reflN(j + 2);
    auto hc = [&](const float* v) {
        return KW0 * (v[jm2] + v[jp2]) + KW1 * (v[jm1] + v[jp1]) + KW2 * v[j];
    };

    // ---- 3) ch1: vconv (centers i0-1..i0+7) into bufB -> hconv -> col diffs
    float acc_iy[SEG];   // accu now; overwritten by iy in step 6
    {
        float a[SEG + 5];
        #pragma unroll
        for (int t = 0; t < SEG + 5; ++t) a[t] = c1[reflN(i0 - 3 + t) * Nn + j];
        #pragma unroll
        for (int r = 0; r < SEG + 1; ++r)
            bufB[r][j] = KW0 * (a[r] + a[r + 4]) + KW1 * (a[r + 1] + a[r + 3]) + KW2 * a[r + 2];
        __syncthreads();                       // B1
        float hprev = hc(&bufB[0][0]);
        #pragma unroll
        for (int r = 0; r < SEG; ++r) {
            float h = hc(&bufB[r + 1][0]);
            float hm = (r == 0 && seg == 0) ? 0.0f : hprev;
            acc_iy[r] = fmaxf((h - hm + TWO255) * INV_SCALE, 0.0f);
            hprev = h;
        }
        __syncthreads();                       // B2: bufB reads done
    }

    // ---- 4) ch0: vconv (centers i0..i0+7) into bufB -> row diffs -> scans
    // hm = h(j-1): fetched from the wave neighbor via shfl_up instead of a
    // second 5-tap conv (saves 5 LDS reads + 5 FMA per row per thread).
    // Wave-boundary lanes (j=64,128,192) and j=0 fixed up in a 1-lane branch.
    float ix[SEG];
    {
        float a[SEG + 4];
        #pragma unroll
        for (int t = 0; t < SEG + 4; ++t) a[t] = c0[reflN(i0 - 2 + t) * Nn + j];
        #pragma unroll
        for (int r = 0; r < SEG; ++r)
            bufB[r][j] = KW0 * (a[r] + a[r + 4]) + KW1 * (a[r + 1] + a[r + 3]) + KW2 * a[r + 2];
        __syncthreads();                       // B3
        #pragma unroll
        for (int r = 0; r < SEG; ++r) {
            const float* v = &bufB[r][0];
            float h  = hc(v);
            float hm = __shfl_up(h, 1, 64);
            if (lane == 0) {
                hm = 0.0f;
                if (j != 0)
                    hm = KW0 * (v[jm3] + v[jp1]) + KW1 * (v[jm2] + v[j]) + KW2 * v[jm1];
            }
            float s = fmaxf((h - hm + TWO255) * INV_SCALE, 0.0f);
            #pragma unroll
            for (int off = 1; off < 64; off <<= 1) {
                float u = __shfl_up(s, off, 64);
                if (lane >= off) s += u;
            }
            ix[r] = s;
            if (lane == 63) wsum[r][wave] = s;
        }
        __syncthreads();  // B4: bufB reads done, wsum visible, c0 DMA drained
    }

    // ---- 5) c1 DMA into bufB (bufB is now free) ----
    issue_prefetch(1, bufB);

    // scan fixup -> sample x-coords
    {
        const float sq_j = seqf(j);
        #pragma unroll
        for (int r = 0; r < SEG; ++r) {
            float add = 0.0f;
            for (int w = 0; w < wave; ++w) add += wsum[r][w];
            float samp = (ix[r] + add) * SCALE - DEF_OFF;
            float p = fminf(fmaxf(samp - sq_j, -PW), PW);
            float g = fminf(fmaxf(p + sq_j, -1.0f), 1.0f);
            ix[r] = (g + 1.0f) * 127.5f;
        }
    }

    // ---- 6) column cumsum with carry -> sample y-coords (in place) ----
    {
        float cum = carry;
        #pragma unroll
        for (int k = 0; k < SEG; ++k) {
            cum += acc_iy[k];
            float samp = cum * SCALE - DEF_OFF;
            float sq = seqf(i0 + k);
            float p  = fminf(fmaxf(samp - sq, -PW), PW);
            float gy = fminf(fmaxf(p + sq, -1.0f), 1.0f);
            acc_iy[k] = (gy + 1.0f) * 127.5f;
        }
    }

    // ---- 7) interp: weights recomputed per channel (keeps live set small)
    // ix in (j-1,j+1), iy in (i-1,i+1) => x0 in {j-1,j}>=0, y0 in {i-1,i}>=0
    auto interp_store = [&](int c, const float (*tile)[Nn]) {
        #pragma unroll
        for (int k = 0; k < SEG; ++k) {
            float fx = floorf(ix[k]), fy = floorf(acc_iy[k]);
            int x0 = (int)fx, y0 = (int)fy;
            float wx1 = ix[k] - fx, wy1 = acc_iy[k] - fy;
            float wx0 = 1.0f - wx1, wy0 = 1.0f - wy1;
            bool vx1 = x0 < Nn - 1, vy1 = y0 < Nn - 1;
            int x1c = min(x0 + 1, Nn - 1);
            int ly0 = y0 - i0 + 1;
            int ly1 = min(y0 + 1, Nn - 1) - i0 + 1;
            float w00 = wx0 * wy0;
            float w10 = vx1 ? wx1 * wy0 : 0.0f;
            float w01 = vy1 ? wx0 * wy1 : 0.0f;
            float w11 = (vx1 && vy1) ? wx1 * wy1 : 0.0f;
            float v = w00 * tile[ly0][x0] + w10 * tile[ly0][x1c]
                    + w01 * tile[ly1][x0] + w11 * tile[ly1][x1c];
            __builtin_nontemporal_store(v, &outp[(((size_t)b * 3 + c) * Nn + (i0 + k)) * Nn + j]);
        }
    };

    interp_store(0, bufA);
    __syncthreads();              // B5: drains c1 DMA, bufA reads done
    issue_prefetch(2, bufA);
    interp_store(1, bufB);
    __syncthreads();              // B6: drains c2 DMA, bufB reads done
    interp_store(2, bufA);
}

}  // namespace

extern "C" void kernel_launch(void* const* d_in, const int* in_sizes, int n_in,
                              void* d_out, int out_size, void* d_ws, size_t ws_size,
                              hipStream_t stream) {
    const float* image = (const float*)d_in[0];   // (B,3,N,N) f32
    const float* prim  = (const float*)d_in[1];   // (B,2,N,N) f32
    float* outp = (float*)d_out;                  // (B,3,N,N) f32
    float* partial = (float*)d_ws;                // B*NSEG*N floats (2MB)

    kP_kernel<<<NSEG * Bn, 256, 0, stream>>>(prim, partial);
    kF_kernel<<<NSEG * Bn, 256, 0, stream>>>(prim, image, partial, outp);
}

// Round 15
// 36.042 us; speedup vs baseline: 1.0700x; 1.0700x over previous
//
#include <hip/hip_runtime.h>

namespace {

constexpr int Nn = 256;
constexpr int Bn = 64;
constexpr int SEG = 8;
constexpr int NSEG = Nn / SEG;   // 32

// Gaussian taps, sigma = 5*0.15+0.35 = 1.1
constexpr float KW0 = 0.07076638f;
constexpr float KW1 = 0.24446039f;
constexpr float KW2 = 0.36954646f;

constexpr float DEF_OFF   = 1.00784313725490196f;   // 1 + 2/255
constexpr float SCALE     = 0.01568627450980392f;   // 4/255
constexpr float INV_SCALE = 63.75f;                 // 255/4
constexpr float TWO255    = 0.00784313725490196f;   // 2/255 = seq step
constexpr float PW        = 0.0078125f;             // 2/256

__device__ __forceinline__ int reflN(int i) {
    if (i < 0) i = -i;
    if (i >= Nn) i = 2 * (Nn - 1) - i;
    return i;
}

__device__ __forceinline__ float seqf(int t) {
    return (float)(2 * t - (Nn - 1)) * (1.0f / (float)(Nn - 1));
}

// Bijective XCD swizzle: 2048 blocks, 8 XCDs, 256-block chunks
// -> all 32 segs of a batch (8 whole batches) share one XCD's L2.
__device__ __forceinline__ void segb(int lin, int& seg, int& b) {
    int wg = (lin & 7) * 256 + (lin >> 3);
    b = wg >> 5;
    seg = wg & (NSEG - 1);
}

// ---- kP: ch1 conv -> per-segment column partial sums (2MB) -----------------
__global__ __launch_bounds__(256, 8) void kP_kernel(const float* __restrict__ prim,
                                                    float* __restrict__ partial) {
    const int j = threadIdx.x;
    int seg, b;
    segb(blockIdx.x, seg, b);
    const int i0 = seg * SEG;
    const float* c1 = prim + ((size_t)b * 2 + 1) * Nn * Nn;

    float a[SEG + 5];
    #pragma unroll
    for (int t = 0; t < SEG + 5; ++t) a[t] = c1[reflN(i0 - 3 + t) * Nn + j];

    __shared__ float vb[(SEG + 1) * Nn];
    #pragma unroll
    for (int r = 0; r < SEG + 1; ++r)   // v-conv centers i0-1 .. i0+7
        vb[r * Nn + j] = KW0 * (a[r] + a[r + 4]) + KW1 * (a[r + 1] + a[r + 3]) + KW2 * a[r + 2];
    __syncthreads();

    const int jm2 = reflN(j - 2), jm1 = reflN(j - 1), jp1 = reflN(j + 1), jp2 = reflN(j + 2);
    auto hc = [&](const float* v) {
        return KW0 * (v[jm2] + v[jp2]) + KW1 * (v[jm1] + v[jp1]) + KW2 * v[j];
    };

    float hprev = hc(&vb[0]);
    float psum = 0.0f;
    #pragma unroll
    for (int r = 0; r < SEG; ++r) {
        float h = hc(&vb[(r + 1) * Nn]);
        float hm = (r == 0 && seg == 0) ? 0.0f : hprev;
        psum += fmaxf((h - hm + TWO255) * INV_SCALE, 0.0f);
        hprev = h;
    }
    partial[((size_t)b * NSEG + seg) * Nn + j] = psum;
}

// ---- kF: conv + scans + cumsum + channel-pipelined bilinear ----------------
// LDS: two 10-row buffers (21KB) -> HW allows 7 blocks/CU.
// bounds(256,4): VGPR cap 128 — the allocator must NOT be forced tighter
// (R8/R9/R11: tighter bounds or bigger arrays => ~100MB scratch spill traffic).
__global__ __launch_bounds__(256, 4) void kF_kernel(const float* __restrict__ prim,
                                                    const float* __restrict__ image,
                                                    const float* __restrict__ partial,
                                                    float* __restrict__ outp) {
    const int j = threadIdx.x;
    int seg, b;
    segb(blockIdx.x, seg, b);
    const int i0 = seg * SEG;
    const int lane = j & 63;
    const int wave = j >> 6;

    __shared__ float bufA[SEG + 2][Nn];   // 10KB
    __shared__ float bufB[SEG + 2][Nn];   // 10KB
    __shared__ float wsum[SEG][4];

    // async image-channel prefetch: 10 rows, one 16B DMA per lane per row
    auto issue_prefetch = [&](int c, float (*buf)[Nn]) {
        for (int r = wave; r < SEG + 2; r += 4) {
            int row = min(max(i0 - 1 + r, 0), Nn - 1);
            const float* src = image + ((size_t)(b * 3 + c) * Nn + row) * Nn + lane * 4;
#if defined(__has_builtin) && __has_builtin(__builtin_amdgcn_global_load_lds)
            __builtin_amdgcn_global_load_lds(
                (const __attribute__((address_space(1))) void*)(const void*)src,
                (__attribute__((address_space(3))) void*)(void*)&buf[r][0],
                16, 0, 0);
#else
            ((float4*)&buf[r][0])[lane] = ((const float4*)(src - lane * 4))[lane];
#endif
        }
    };

    // ---- 1) start c0 DMA immediately (overlaps both conv phases) ----
    issue_prefetch(0, bufA);

    const float* c0 = prim + (size_t)b * 2 * Nn * Nn;
    const float* c1 = c0 + (size_t)Nn * Nn;

    // ---- 2) exclusive carry over preceding segments (L2-resident) ----
    const float* pb = partial + (size_t)b * NSEG * Nn + j;
    float carry = 0.0f;
    #pragma unroll
    for (int k = 0; k < NSEG - 1; ++k) {
        float p = pb[(size_t)k * Nn];
        carry += (k < seg) ? p : 0.0f;
    }

    const int jm3 = reflN(j - 3), jm2 = reflN(j - 2), jm1 = reflN(j - 1),
              jp1 = reflN(j + 1), jp2 = reflN(j + 2);
    auto hc = [&](const float* v) {
        return KW0 * (v[jm2] + v[jp2]) + KW1 * (v[jm1] + v[jp1]) + KW2 * v[j];
    };

    // ---- 3) ch1: vconv (centers i0-1..i0+7) into bufB -> hconv -> col diffs
    float acc_iy[SEG];   // accu now; overwritten by iy in step 6
    {
        float a[SEG + 5];
        #pragma unroll
        for (int t = 0; t < SEG + 5; ++t) a[t] = c1[reflN(i0 - 3 + t) * Nn + j];
        #pragma unroll
        for (int r = 0; r < SEG + 1; ++r)
            bufB[r][j] = KW0 * (a[r] + a[r + 4]) + KW1 * (a[r + 1] + a[r + 3]) + KW2 * a[r + 2];
        __syncthreads();                       // B1
        float hprev = hc(&bufB[0][0]);
        #pragma unroll
        for (int r = 0; r < SEG; ++r) {
            float h = hc(&bufB[r + 1][0]);
            float hm = (r == 0 && seg == 0) ? 0.0f : hprev;
            acc_iy[r] = fmaxf((h - hm + TWO255) * INV_SCALE, 0.0f);
            hprev = h;
        }
        __syncthreads();                       // B2: bufB reads done
    }

    // ---- 4) ch0: vconv (centers i0..i0+7) into bufB -> row diffs -> scans
    float ix[SEG];
    {
        float a[SEG + 4];
        #pragma unroll
        for (int t = 0; t < SEG + 4; ++t) a[t] = c0[reflN(i0 - 2 + t) * Nn + j];
        #pragma unroll
        for (int r = 0; r < SEG; ++r)
            bufB[r][j] = KW0 * (a[r] + a[r + 4]) + KW1 * (a[r + 1] + a[r + 3]) + KW2 * a[r + 2];
        __syncthreads();                       // B3
        #pragma unroll
        for (int r = 0; r < SEG; ++r) {
            const float* v = &bufB[r][0];
            float h  = hc(v);
            float hm = KW0 * (v[jm3] + v[jp1]) + KW1 * (v[jm2] + v[j]) + KW2 * v[jm1];
            if (j == 0) hm = 0.0f;
            float s = fmaxf((h - hm + TWO255) * INV_SCALE, 0.0f);
            #pragma unroll
            for (int off = 1; off < 64; off <<= 1) {
                float u = __shfl_up(s, off, 64);
                if (lane >= off) s += u;
            }
            ix[r] = s;
            if (lane == 63) wsum[r][wave] = s;
        }
        __syncthreads();  // B4: bufB reads done, wsum visible, c0 DMA drained
    }

    // ---- 5) c1 DMA into bufB (bufB is now free) ----
    issue_prefetch(1, bufB);

    // scan fixup -> sample x-coords
    {
        const float sq_j = seqf(j);
        #pragma unroll
        for (int r = 0; r < SEG; ++r) {
            float add = 0.0f;
            for (int w = 0; w < wave; ++w) add += wsum[r][w];
            float samp = (ix[r] + add) * SCALE - DEF_OFF;
            float p = fminf(fmaxf(samp - sq_j, -PW), PW);
            float g = fminf(fmaxf(p + sq_j, -1.0f), 1.0f);
            ix[r] = (g + 1.0f) * 127.5f;
        }
    }

    // ---- 6) column cumsum with carry -> sample y-coords (in place) ----
    {
        float cum = carry;
        #pragma unroll
        for (int k = 0; k < SEG; ++k) {
            cum += acc_iy[k];
            float samp = cum * SCALE - DEF_OFF;
            float sq = seqf(i0 + k);
            float p  = fminf(fmaxf(samp - sq, -PW), PW);
            float gy = fminf(fmaxf(p + sq, -1.0f), 1.0f);
            acc_iy[k] = (gy + 1.0f) * 127.5f;
        }
    }

    // ---- 7) interp. Key facts: samp clipped to [-1,1] => ix,iy in [0,255]
    // EXACTLY, so boundary weights are naturally zero (wx1=0 at x0=255) — no
    // validity logic needed. Unconditional neighbor reads p0[0],p0[1] and
    // p0[256],p0[257] pair into ds_read2_b32 (96 -> 48 LDS instr/thread);
    // weight-0 overreads land in adjacent initialized (finite) LDS.
    // ly0 <= 8 always (iy < i0+8), so row ly0+1 stays inside the 10-row tile.
    auto interp_store = [&](int c, const float (*tile)[Nn]) {
        #pragma unroll
        for (int k = 0; k < SEG; ++k) {
            float fx = floorf(ix[k]), fy = floorf(acc_iy[k]);
            float wx1 = ix[k] - fx, wy1 = acc_iy[k] - fy;
            int x0 = (int)fx;
            int ly0 = (int)fy - i0 + 1;
            const float* p0 = &tile[ly0][x0];
            float v00 = p0[0],  v10 = p0[1];
            float v01 = p0[Nn], v11 = p0[Nn + 1];
            float top = v00 + wx1 * (v10 - v00);
            float bot = v01 + wx1 * (v11 - v01);
            float v = top + wy1 * (bot - top);
            __builtin_nontemporal_store(v, &outp[(((size_t)b * 3 + c) * Nn + (i0 + k)) * Nn + j]);
        }
    };

    interp_store(0, bufA);
    __syncthreads();              // B5: drains c1 DMA, bufA reads done
    issue_prefetch(2, bufA);
    interp_store(1, bufB);
    __syncthreads();              // B6: drains c2 DMA, bufB reads done
    interp_store(2, bufA);
}

}  // namespace

extern "C" void kernel_launch(void* const* d_in, const int* in_sizes, int n_in,
                              void* d_out, int out_size, void* d_ws, size_t ws_size,
                              hipStream_t stream) {
    const float* image = (const float*)d_in[0];   // (B,3,N,N) f32
    const float* prim  = (const float*)d_in[1];   // (B,2,N,N) f32
    float* outp = (float*)d_out;                  // (B,3,N,N) f32
    float* partial = (float*)d_ws;                // B*NSEG*N floats (2MB)

    kP_kernel<<<NSEG * Bn, 256, 0, stream>>>(prim, partial);
    kF_kernel<<<NSEG * Bn, 256, 0, stream>>>(prim, image, partial, outp);
}